// Round 4
// baseline (758.828 us; speedup 1.0000x reference)
//
#include <hip/hip_runtime.h>
#include <cstdint>

// ---------------- problem constants ----------------
#define LVLPOS 75240          // 10*66*114 flat padded positions per level
#define GUARD  256            // zero guard positions before/after imgP data
#define NPART  16             // stats partial copies
#define FLVL32 4816896        // fdat per-level stride in u32 (75264*64)

using f32x4  = __attribute__((ext_vector_type(4))) float;
using bf16x8 = __attribute__((ext_vector_type(8))) __bf16;

static __device__ __forceinline__ unsigned short f2bf(float f) {
  unsigned int u = __float_as_uint(f);
  u += 0x7fffu + ((u >> 16) & 1u);     // round-to-nearest-even
  return (unsigned short)(u >> 16);
}
static __device__ __forceinline__ float bflo(uint32_t d) { return __uint_as_float(d << 16); }
static __device__ __forceinline__ float bfhi(uint32_t d) { return __uint_as_float(d & 0xffff0000u); }

#if __has_builtin(__builtin_amdgcn_global_load_lds)
#define HAVE_GLL 1
typedef const __attribute__((address_space(1))) unsigned int* gas1_t;
typedef __attribute__((address_space(3))) unsigned int* las3_t;
static __device__ __forceinline__ void gll16(const void* g, void* l) {
  __builtin_amdgcn_global_load_lds((gas1_t)g, (las3_t)l, 16, 0, 0);
}
#else
#define HAVE_GLL 0
#endif

// ---------------- ws layout (bytes) ----------------
// wf     : [3][ck64:4][tap:9][frag 8192] bf16                            1,769,472
// bias   : [3][128] f32 (per-level folded bias)                               1,536
// pts_wb : [128][128] bf16 fragment-major                                   32,768
// statsP : [16][512] f32 partials                                           32,768
// fdat   : [3][75264][128] bf16 (per-level conv out, padded layout)     57,802,752
// imgP   : [(256+3*75240+256)][256] bf16 flat padded NHWC              115,830,784
// img_raw/pts_raw (33,554,432 each) ALIAS imgP (dead after k_conv)
#define OFF_WF     ((size_t)0)
#define OFF_BIAS   ((size_t)1769472)
#define OFF_PTSWB  ((size_t)1771008)
#define OFF_STATSP ((size_t)1803776)
#define OFF_FDAT   ((size_t)1836544)
#define OFF_IMGP   ((size_t)59639296)
#define OFF_IRAW   OFF_IMGP
#define OFF_PRAW   (OFF_IMGP + (size_t)33554432)

// =====================================================================
// setup: fold weights (432), zero imgP guards/pad-rows (62),
// bias + pts prepack (65), zero statsP (8).  grid 567.
// =====================================================================
__global__ __launch_bounds__(256) void k_setup(const float* __restrict__ img_w,
                                               const float* __restrict__ conv_w,
                                               const float* __restrict__ conv_b,
                                               const float* __restrict__ pts_w,
                                               unsigned short* __restrict__ wf,
                                               float* __restrict__ bias,
                                               unsigned short* __restrict__ pts_wb,
                                               unsigned short* __restrict__ imgP,
                                               float* __restrict__ statsP) {
  __shared__ float smem[12544];
  const int b = blockIdx.x, t = threadIdx.x;
  if (b < 432) {
    int z = b >> 1, oh = b & 1;
    int l = z / 72, r = z % 72, tap = r / 8, ckk = r % 8;
    float* iw = smem;                           // [64 o][130]
    float* cw = smem + 8320;                    // [128 mid][33]
    for (int v = t; v < 2048; v += 256) {
      int o = v >> 5, seg = v & 31;
      float4 f = *(const float4*)(img_w + (size_t)(oh * 64 + o) * 384 + l * 128 + seg * 4);
      float* d = iw + o * 130 + seg * 4;
      d[0] = f.x; d[1] = f.y; d[2] = f.z; d[3] = f.w;
    }
    for (int v = t; v < 4096; v += 256) {
      int mid = v >> 5, cj = v & 31;
      cw[mid * 33 + cj] = conv_w[(size_t)((l * 128 + mid) * 256 + ckk * 32 + cj) * 9 + tap];
    }
    __syncthreads();
    const int o64 = t & 63, cs = t >> 6, o = oh * 64 + o64;
    float accs[8];
    #pragma unroll
    for (int ci = 0; ci < 8; ++ci) accs[ci] = 0.f;
    for (int mid = 0; mid < 128; ++mid) {
      float a = iw[o64 * 130 + mid];
      #pragma unroll
      for (int ci = 0; ci < 8; ++ci) accs[ci] = fmaf(a, cw[mid * 33 + cs * 8 + ci], accs[ci]);
    }
    #pragma unroll
    for (int ci = 0; ci < 8; ++ci) {
      int c = ckk * 32 + cs * 8 + ci;
      int ck64 = c >> 6, c64 = c & 63;
      int kh = c64 >> 5, kq3 = (c64 >> 3) & 3, el = c64 & 7;
      size_t idx = (size_t)((l * 4 + ck64) * 9 + tap) * 8192
                 + (size_t)(((o >> 4) * 2 + kh) * 512) + ((o & 15) + 16 * kq3) * 8 + el;
      wf[idx] = f2bf(accs[ci]);
    }
  } else if (b < 494) {
    int z = b - 432;
    size_t base; int n16;
    if (z == 60)      { base = 0; n16 = 8192; }
    else if (z == 61) { base = (size_t)(GUARD + 3 * LVLPOS) * 256; n16 = 8192; }
    else {
      int lvl = z / 20, w = z % 20, n = w >> 1, y = (w & 1) ? 65 : 0;
      base = (size_t)(GUARD + lvl * LVLPOS + (n * 66 + y) * 114) * 256; n16 = 3648;
    }
    uint4 zz = {0u, 0u, 0u, 0u};
    uint4* d = (uint4*)(imgP + base);
    for (int v = t; v < n16; v += 256) d[v] = zz;
  } else if (b < 559) {
    int z = b - 494;
    if (z == 0) {
      if (t < 128) {
        for (int l = 0; l < 3; ++l) {
          float a = 0.f;
          for (int mid = 0; mid < 128; ++mid)
            a = fmaf(img_w[t * 384 + l * 128 + mid], conv_b[l * 128 + mid], a);
          bias[l * 128 + t] = a;
        }
      }
    } else {
      int idx = (z - 1) * 256 + t;
      int o = idx >> 7, k = idx & 127;
      int ks = k >> 5, kq = (k >> 3) & 3, el = k & 7;
      int pos = (ks * 8 + (o >> 4)) * 512 + ((o & 15) + 16 * kq) * 8 + el;
      pts_wb[pos] = f2bf(pts_w[idx]);
    }
  } else {
    int z = b - 559;
    ((float4*)statsP)[z * 256 + t] = (float4){0.f, 0.f, 0.f, 0.f};
  }
}

// =====================================================================
// NCHW fp32 -> flat padded NHWC bf16, channel-half split.
// grid 3840 = (lvl, n, y, half); LDS tile32[112][65] u32 = 29,120 B.
// =====================================================================
__global__ __launch_bounds__(256) void k_nhwc(const float* __restrict__ img,
                                              unsigned short* __restrict__ imgP) {
  __shared__ uint32_t tile32[7280];            // [x 112][cp 64], pitch 65
  const int t = threadIdx.x;
  const int lvl = blockIdx.x / 1280;
  const int r = blockIdx.x % 1280;
  const int n = r >> 7, w = r & 127, y = w >> 1, half = w & 1;
  const float4* src4 = (const float4*)(img + (size_t)(lvl * 10 + n) * 1835008
                                       + (size_t)(half * 128) * 7168 + (size_t)y * 112);
  // phase 1: load 2 channels x 4 x, pack pairs, LDS scatter
  for (int v = t; v < 1792; v += 256) {
    int s = v % 28, a = v / 28;                // a = channel pair 0..63, s = x/4
    float4 f0 = src4[(size_t)(2 * a) * 1792 + s];
    float4 f1 = src4[(size_t)(2 * a + 1) * 1792 + s];
    uint32_t* dst = tile32 + (4 * s) * 65 + a;
    dst[0]      = (uint32_t)f2bf(f0.x) | ((uint32_t)f2bf(f1.x) << 16);
    dst[65]     = (uint32_t)f2bf(f0.y) | ((uint32_t)f2bf(f1.y) << 16);
    dst[130]    = (uint32_t)f2bf(f0.z) | ((uint32_t)f2bf(f1.z) << 16);
    dst[195]    = (uint32_t)f2bf(f0.w) | ((uint32_t)f2bf(f1.w) << 16);
  }
  __syncthreads();
  // phase 2: conflict-free b32 reads, coalesced 256 B stores (incl. x-pads)
  uint32_t* dst32 = (uint32_t*)(imgP + (size_t)(GUARD + lvl * LVLPOS + (n * 66 + y + 1) * 114) * 256)
                  + half * 64;
  for (int v = t; v < 7296; v += 256) {
    int xp = v >> 6, a = v & 63;
    uint32_t val = 0;
    if (xp >= 1 && xp <= 112) val = tile32[(xp - 1) * 65 + a];
    dst32[(size_t)xp * 128 + a] = val;
  }
}

// =====================================================================
// Conv, level-split: grid 1764 = (lvl, m-tile); M=128 flat pos, N=128,
// K=2304 per level as 12 (ck,ky) stages x 3 kx sub-stages.
// A halo in LDS (130 x pitch 72); B double-buffered via global_load_lds.
// LDS 51,488 B -> 3 blocks/CU.
// =====================================================================
__global__ __launch_bounds__(256, 3) void k_conv(const unsigned short* __restrict__ imgP,
                                                 const unsigned short* __restrict__ wf,
                                                 const float* __restrict__ bias,
                                                 unsigned short* __restrict__ fdat) {
  __shared__ unsigned short lds[9360 + 2 * 8192];
  unsigned short* As = lds;
  unsigned short* Bs = lds + 9360;
  const int t = threadIdx.x, lane = t & 63, wave = t >> 6;
  const int mh = wave & 1, nh = wave >> 1;
  const int m = lane & 15, kq = lane >> 4;
  const int lvl = blockIdx.x / 588;
  const int m0 = (blockIdx.x % 588) * 128;

  f32x4 acc[4][4];
  #pragma unroll
  for (int i = 0; i < 4; ++i)
    #pragma unroll
    for (int j = 0; j < 4; ++j) acc[i][j] = (f32x4){0.f, 0.f, 0.f, 0.f};

  const unsigned short* Alvl = imgP + ((size_t)GUARD + (size_t)lvl * LVLPOS + m0 - 1) * 256;
  const unsigned short* Wlvl = wf + (size_t)lvl * 4 * 9 * 8192;

  #pragma unroll 1
  for (int s = 0; s < 12; ++s) {
    const int ck = s >> 2 == 3 ? 3 : s / 3;    // s/3
    const int ck_ = s / 3, ky = s - ck_ * 3;
    // ---- stage A halo (130 pos x 64 c, pitch 72) ----
    const unsigned short* Asrc = Alvl + (ptrdiff_t)(ky - 1) * 114 * 256 + ck_ * 64;
    for (int v = t; v < 1040; v += 256) {
      int p = v >> 3, seg = v & 7;
      uint4 d = *(const uint4*)(Asrc + (size_t)p * 256 + seg * 8);
      *(uint4*)(As + p * 72 + seg * 8) = d;
    }
    // ---- stage B tap kx=0 into buf0 ----
    const unsigned short* Bsrc = Wlvl + (size_t)(ck_ * 9 + ky * 3) * 8192;
#if HAVE_GLL
    #pragma unroll
    for (int i = 0; i < 4; ++i) {
      int chunk = wave * 4 + i;
      gll16(Bsrc + chunk * 512 + lane * 8, Bs + chunk * 512);
    }
#else
    for (int v = t; v < 1024; v += 256)
      *(uint4*)(Bs + v * 8) = *(const uint4*)(Bsrc + v * 8);
#endif
    __syncthreads();
    #pragma unroll
    for (int kx = 0; kx < 3; ++kx) {
      if (kx < 2) {
        const unsigned short* Bn = Bsrc + (kx + 1) * 8192;
        unsigned short* Bd = Bs + ((kx + 1) & 1) * 8192;
#if HAVE_GLL
        #pragma unroll
        for (int i = 0; i < 4; ++i) {
          int chunk = wave * 4 + i;
          gll16(Bn + chunk * 512 + lane * 8, Bd + chunk * 512);
        }
#else
        for (int v = t; v < 1024; v += 256)
          *(uint4*)(Bd + v * 8) = *(const uint4*)(Bn + v * 8);
#endif
      }
      const unsigned short* Bb = Bs + (kx & 1) * 8192;
      bf16x8 bfr[4][2];
      #pragma unroll
      for (int nt = 0; nt < 4; ++nt) {
        const unsigned short* bp = Bb + ((nh * 4 + nt) * 2) * 512 + lane * 8;
        bfr[nt][0] = *(const bf16x8*)(bp);
        bfr[nt][1] = *(const bf16x8*)(bp + 512);
      }
      #pragma unroll
      for (int mt = 0; mt < 4; ++mt) {
        const unsigned short* ap = As + (mh * 64 + mt * 16 + m + kx) * 72 + kq * 8;
        bf16x8 a0 = *(const bf16x8*)(ap);
        bf16x8 a1 = *(const bf16x8*)(ap + 32);
        #pragma unroll
        for (int nt = 0; nt < 4; ++nt) {
          acc[mt][nt] = __builtin_amdgcn_mfma_f32_16x16x32_bf16(a0, bfr[nt][0], acc[mt][nt], 0, 0, 0);
          acc[mt][nt] = __builtin_amdgcn_mfma_f32_16x16x32_bf16(a1, bfr[nt][1], acc[mt][nt], 0, 0, 0);
        }
      }
      __syncthreads();
    }
  }

  // ---- epilogue: per-level bias + bf16, LDS repack, contiguous store ----
  unsigned short* Ep = lds;                     // [128][128]
  #pragma unroll
  for (int nt = 0; nt < 4; ++nt) {
    int oc = nh * 64 + nt * 16 + m;
    float bv = bias[lvl * 128 + oc];
    #pragma unroll
    for (int mt = 0; mt < 4; ++mt)
      #pragma unroll
      for (int rr = 0; rr < 4; ++rr)
        Ep[(mh * 64 + mt * 16 + kq * 4 + rr) * 128 + oc] = f2bf(acc[mt][nt][rr] + bv);
  }
  __syncthreads();
  unsigned short* dst = fdat + (size_t)lvl * 9633792 + (size_t)m0 * 128;
  for (int v = t; v < 2048; v += 256)
    *(uint4*)(dst + v * 8) = *(const uint4*)(Ep + v * 8);
}

// =====================================================================
// gather (blocks 0..8191, 3-level fdat) + pts GEMM (8192..9215), stats fused
// =====================================================================
__global__ __launch_bounds__(256) void k_gp(const float* __restrict__ pts_xyz,
                                            const int* __restrict__ cam_ids,
                                            const float* __restrict__ Tm,
                                            const float* __restrict__ Km,
                                            const unsigned short* __restrict__ fdat,
                                            const float* __restrict__ pts_feats,
                                            const unsigned short* __restrict__ pts_wb,
                                            unsigned short* __restrict__ img_raw,
                                            unsigned short* __restrict__ pts_raw,
                                            float* __restrict__ statsP) {
  __shared__ __align__(16) char smem[36864];
  const int t = threadIdx.x, lane = t & 63, wave = t >> 6;

  if (blockIdx.x < 8192) {
    float* sb = (float*)smem;
    float* qb = sb + 128;
    if (t < 128) { sb[t] = 0.f; sb[128 + t] = 0.f; }
    __syncthreads();
    const int p0 = blockIdx.x * 16 + wave * 4;
    const uint32_t* fq = (const uint32_t*)fdat;
    for (int j = 0; j < 4; ++j) {
      const int p = p0 + j;
      const int b = p >> 16;
      const int cam = cam_ids[p];
      const float X = pts_xyz[(size_t)p * 3], Y = pts_xyz[(size_t)p * 3 + 1], Z = pts_xyz[(size_t)p * 3 + 2];
      const float* Tc = Tm + cam * 16;
      float pcx = Tc[0] * X + Tc[1] * Y + Tc[2]  * Z + Tc[3];
      float pcy = Tc[4] * X + Tc[5] * Y + Tc[6]  * Z + Tc[7];
      float pcz = Tc[8] * X + Tc[9] * Y + Tc[10] * Z + Tc[11];
      const float* Kc = Km + cam * 9;
      float pimx = Kc[0] * 0.125f * pcx + Kc[1] * pcy          + Kc[2] * 0.125f * pcz;
      float pimy = Kc[3] * pcx          + Kc[4] * 0.125f * pcy + Kc[5] * 0.125f * pcz;
      float pimz = Kc[6] * pcx          + Kc[7] * pcy          + Kc[8] * pcz;
      float u = pimx / pimz, vv = pimy / pimz;
      float px = (u / 112.f) * 111.f;
      float py = (vv / 64.f) * 63.f;
      float x0 = floorf(px), y0 = floorf(py);
      float wx = px - x0, wy = py - y0;
      float cxf[4] = {x0, x0 + 1.f, x0, x0 + 1.f};
      float cyf[4] = {y0, y0, y0 + 1.f, y0 + 1.f};
      float cwt[4] = {(1.f - wx) * (1.f - wy), wx * (1.f - wy), (1.f - wx) * wy, wx * wy};
      const int nimg = b * 5 + cam;
      float wv[4]; int idx[4]; bool any = false;
      #pragma unroll
      for (int c4 = 0; c4 < 4; ++c4) {
        float xf = cxf[c4], yf = cyf[c4];
        bool valid = (xf >= 0.f) && (xf <= 111.f) && (yf >= 0.f) && (yf <= 63.f);
        float w = cwt[c4] * (valid ? 1.f : 0.f);
        int xi = (int)fminf(fmaxf(xf, 0.f), 111.f);
        int yi = (int)fminf(fmaxf(yf, 0.f), 63.f);
        wv[c4] = w;
        idx[c4] = (nimg * 66 + yi + 1) * 114 + xi + 1;
        any = any || (w != 0.f);
      }
      float a0 = 0.f, a1 = 0.f;
      if (any) {
        #pragma unroll
        for (int c4 = 0; c4 < 4; ++c4) {
          const uint32_t* q = fq + (size_t)idx[c4] * 64 + lane;
          float w = wv[c4];
          #pragma unroll
          for (int lv = 0; lv < 3; ++lv) {
            uint32_t d = q[(size_t)lv * FLVL32];
            a0 = fmaf(w, bflo(d), a0);
            a1 = fmaf(w, bfhi(d), a1);
          }
        }
      }
      float s0 = a0, q0 = a0 * a0, s1 = a1, q1 = a1 * a1;
      atomicAdd(&sb[lane * 2], s0);
      atomicAdd(&sb[lane * 2 + 1], s1);
      atomicAdd(&qb[lane * 2], q0);
      atomicAdd(&qb[lane * 2 + 1], q1);
      ((uint32_t*)img_raw)[(size_t)p * 64 + lane] =
          (uint32_t)f2bf(a0) | ((uint32_t)f2bf(a1) << 16);
    }
    __syncthreads();
    if (t < 128) {
      float* sp = statsP + (size_t)(blockIdx.x & (NPART - 1)) * 512;
      atomicAdd(sp + t, sb[t]);
      atomicAdd(sp + 128 + t, qb[t]);
    }
  } else {
    const int pb = blockIdx.x - 8192;
    const size_t r0 = (size_t)pb * 128;
    unsigned short* As2 = (unsigned short*)smem;     // [128][136]
    const int mh = wave & 1, nh = wave >> 1;
    const int m = lane & 15, kq = lane >> 4;
    for (int v = t; v < 4096; v += 256) {
      int mm = v >> 5, seg = v & 31;
      float4 f = *(const float4*)(pts_feats + (r0 + mm) * 128 + seg * 4);
      uint2 d;
      d.x = (uint32_t)f2bf(f.x) | ((uint32_t)f2bf(f.y) << 16);
      d.y = (uint32_t)f2bf(f.z) | ((uint32_t)f2bf(f.w) << 16);
      *(uint2*)(As2 + mm * 136 + seg * 4) = d;
    }
    __syncthreads();
    f32x4 acc[4][4];
    #pragma unroll
    for (int i = 0; i < 4; ++i)
      #pragma unroll
      for (int jj = 0; jj < 4; ++jj) acc[i][jj] = (f32x4){0.f, 0.f, 0.f, 0.f};
    #pragma unroll
    for (int ks = 0; ks < 4; ++ks) {
      bf16x8 bv[4];
      #pragma unroll
      for (int nt = 0; nt < 4; ++nt)
        bv[nt] = *(const bf16x8*)(pts_wb + (size_t)((ks * 8 + nh * 4 + nt) * 512) + lane * 8);
      #pragma unroll
      for (int mt = 0; mt < 4; ++mt) {
        bf16x8 af = *(const bf16x8*)(As2 + (mh * 64 + mt * 16 + m) * 136 + ks * 32 + kq * 8);
        #pragma unroll
        for (int nt = 0; nt < 4; ++nt)
          acc[mt][nt] = __builtin_amdgcn_mfma_f32_16x16x32_bf16(af, bv[nt], acc[mt][nt], 0, 0, 0);
      }
    }
    __syncthreads();
    #pragma unroll
    for (int mt = 0; mt < 4; ++mt)
      #pragma unroll
      for (int nt = 0; nt < 4; ++nt)
        #pragma unroll
        for (int rr = 0; rr < 4; ++rr)
          As2[(mh * 64 + mt * 16 + kq * 4 + rr) * 128 + nh * 64 + nt * 16 + m] = f2bf(acc[mt][nt][rr]);
    __syncthreads();
    unsigned short* dst = pts_raw + r0 * 128;
    for (int v = t; v < 2048; v += 256)
      *(uint4*)(dst + v * 8) = *(const uint4*)(As2 + v * 8);
    float* ps = (float*)(smem + 34816);
    float* pq = (float*)(smem + 35840);
    {
      int col = t & 127, rh = t >> 7;
      float s = 0.f, q = 0.f;
      for (int i = 0; i < 64; ++i) {
        float v = __uint_as_float((uint32_t)As2[(rh * 64 + i) * 128 + col] << 16);
        s += v; q += v * v;
      }
      ps[rh * 128 + col] = s;
      pq[rh * 128 + col] = q;
    }
    __syncthreads();
    if (t < 128) {
      float* sp = statsP + (size_t)(blockIdx.x & (NPART - 1)) * 512;
      atomicAdd(sp + 256 + t, ps[t] + ps[128 + t]);
      atomicAdd(sp + 384 + t, pq[t] + pq[128 + t]);
    }
  }
}

// =====================================================================
// finalize: reduce statsP, out = relu(a_img*img + a_pts*pts + c), fp32
// =====================================================================
__global__ __launch_bounds__(256) void k_final(const unsigned short* __restrict__ img_raw,
                                               const unsigned short* __restrict__ pts_raw,
                                               const float* __restrict__ statsP,
                                               const float* __restrict__ img_gamma,
                                               const float* __restrict__ img_beta,
                                               const float* __restrict__ pts_gamma,
                                               const float* __restrict__ pts_beta,
                                               float* __restrict__ out) {
  __shared__ float sA[128], sB[128], sC[128];
  const int t = threadIdx.x;
  if (t < 128) {
    float si = 0.f, qi = 0.f, sp = 0.f, qp = 0.f;
    for (int k = 0; k < NPART; ++k) {
      const float* st = statsP + (size_t)k * 512;
      si += st[t]; qi += st[128 + t]; sp += st[256 + t]; qp += st[384 + t];
    }
    const float Nr = 131072.f;
    float mu_i = si / Nr;
    float var_i = qi / Nr - mu_i * mu_i;
    float a_i = img_gamma[t] * rsqrtf(var_i + 1e-3f);
    float mu_p = sp / Nr;
    float var_p = qp / Nr - mu_p * mu_p;
    float a_p = pts_gamma[t] * rsqrtf(var_p + 1e-3f);
    sA[t] = a_i; sB[t] = a_p;
    sC[t] = img_beta[t] + pts_beta[t] - a_i * mu_i - a_p * mu_p;
  }
  __syncthreads();
  const uint32_t* ir = (const uint32_t*)img_raw;
  const uint32_t* pr = (const uint32_t*)pts_raw;
  size_t g0 = (size_t)blockIdx.x * 2048;
  for (int i = 0; i < 8; ++i) {
    size_t g = g0 + i * 256 + t;
    uint32_t di = ir[g], dp = pr[g];
    int c = (int)(g & 63) * 2;
    float o0 = fmaxf(0.f, sA[c] * bflo(di) + sB[c] * bflo(dp) + sC[c]);
    float o1 = fmaxf(0.f, sA[c + 1] * bfhi(di) + sB[c + 1] * bfhi(dp) + sC[c + 1]);
    float2 o; o.x = o0; o.y = o1;
    *(float2*)(out + g * 2) = o;
  }
}

// =====================================================================
extern "C" void kernel_launch(void* const* d_in, const int* in_sizes, int n_in,
                              void* d_out, int out_size, void* d_ws, size_t ws_size,
                              hipStream_t stream) {
  const float* img_feats = (const float*)d_in[0];
  const float* pts_xyz   = (const float*)d_in[1];
  const float* pts_feats = (const float*)d_in[2];
  const float* Tm        = (const float*)d_in[3];
  const float* Km        = (const float*)d_in[4];
  const float* conv_w    = (const float*)d_in[5];
  const float* conv_b    = (const float*)d_in[6];
  const float* img_w     = (const float*)d_in[7];
  // d_in[8] img_b, d_in[12] pts_b cancel under BN mean subtraction
  const float* img_gamma = (const float*)d_in[9];
  const float* img_beta  = (const float*)d_in[10];
  const float* pts_w     = (const float*)d_in[11];
  const float* pts_gamma = (const float*)d_in[13];
  const float* pts_beta  = (const float*)d_in[14];
  const int*   cam_ids   = (const int*)d_in[15];

  char* wsb = (char*)d_ws;
  unsigned short* wf      = (unsigned short*)(wsb + OFF_WF);
  float*          bias    = (float*)(wsb + OFF_BIAS);
  unsigned short* pts_wb  = (unsigned short*)(wsb + OFF_PTSWB);
  float*          statsP  = (float*)(wsb + OFF_STATSP);
  unsigned short* fdat    = (unsigned short*)(wsb + OFF_FDAT);
  unsigned short* imgP    = (unsigned short*)(wsb + OFF_IMGP);
  unsigned short* img_raw = (unsigned short*)(wsb + OFF_IRAW);
  unsigned short* pts_raw = (unsigned short*)(wsb + OFF_PRAW);

  k_setup<<<dim3(567), dim3(256), 0, stream>>>(img_w, conv_w, conv_b, pts_w,
                                               wf, bias, pts_wb, imgP, statsP);
  k_nhwc<<<dim3(3840), dim3(256), 0, stream>>>(img_feats, imgP);
  k_conv<<<dim3(1764), dim3(256), 0, stream>>>(imgP, wf, bias, fdat);
  k_gp<<<dim3(9216), dim3(256), 0, stream>>>(pts_xyz, cam_ids, Tm, Km, fdat,
                                             pts_feats, pts_wb, img_raw, pts_raw, statsP);
  k_final<<<dim3(4096), dim3(256), 0, stream>>>(img_raw, pts_raw, statsP,
                                                img_gamma, img_beta, pts_gamma, pts_beta,
                                                (float*)d_out);
}